// Round 1
// 66.955 us; speedup vs baseline: 1.0663x; 1.0663x over previous
//
#include <hip/hip_runtime.h>

// Heisenberg-picture reformulation.
//
//   z_q = <psi| P0' R1' P1' Z_q P1 R1 P0 |psi>,  |psi> = product state from
//   embed-RY + L0-RY (angles add) + L0-RZ.  L1-RZ commutes with Z-strings
//   (dropped).  P1 pullback keeps Z-strings; R1 pullback: Z -> cos a*Z - sin a*X;
//   P0 pullback is a Pauli automorphism.  On the product state each Pauli
//   string factorizes:  <Z_j>=cosA_j, <X_j>=sinA_j*cos z_j, <Y_j>=sinA_j*sin z_j
//   with A_j = pi*tanh(x_j) + w[0,j,0], z_j = w[0,j,1].
//
//   => z_q = sum_t K_t * prod_j {cosA_j | sinA_j},  36 terms total,
//   all K_t uniform (functions of w only) -> computed once in setup kernel,
//   consumed via scalar loads.  Per sample: 4x{exp,rcp,cos,sin} + ~90 VALU.

__global__ void qsetup_kernel(const float* __restrict__ w, float* __restrict__ k)
{
    if (threadIdx.x != 0) return;
    float c[4], s[4], cz[4], sz[4];
#pragma unroll
    for (int j = 0; j < 4; ++j) {
        float a1 = w[8 + 2 * j];          // layer1 RY full angle
        c[j] = __cosf(a1); s[j] = __sinf(a1);
        float zz = w[2 * j + 1];          // layer0 RZ full angle
        cz[j] = __cosf(zz); sz[j] = __sinf(zz);
    }
    // ---- z0 terms (pullback of Z1Z2Z3) ----
    k[0] =  c[1]*c[2]*c[3];                          // C0*C1*C3
    k[1] = -c[1]*c[2]*s[3]*cz[0]*cz[1]*cz[3];        // S0*S1*C2*S3
    k[2] =  c[1]*s[2]*c[3]*sz[2]*sz[3];              // S2*S3
    k[3] = -s[1]*c[2]*c[3]*cz[1]*cz[2];              // S1*S2*C3
    k[4] = -c[1]*s[2]*s[3]*sz[0]*sz[1]*cz[2];        // S0*S1*S2
    k[5] = -s[1]*c[2]*s[3]*sz[0]*sz[2]*cz[3];        // S0*C1*S2*S3
    k[6] = -s[1]*s[2]*c[3]*sz[1]*sz[3];              // C0*S1*C2*S3
    k[7] = -s[1]*s[2]*s[3]*cz[0];                    // S0
    // ---- z1 terms (pullback of Z0Z1) ----
    k[8]  =  c[0]*c[1];                              // C0*C2*C3
    k[9]  =  c[0]*s[1]*sz[1]*sz[2];                  // S1*S2*C3
    k[10] =  s[0]*c[1]*sz[0]*sz[1];                  // S0*S1
    k[11] =  s[0]*s[1]*cz[0]*cz[2];                  // S0*S2
    // ---- z2 terms (pullback of Z0Z1Z2) ----
    k[12] =  c[0]*c[1]*c[2];                         // C1*C3
    k[13] =  c[0]*c[1]*s[2]*sz[2]*sz[3];             // C0*S2*S3
    k[14] = -c[0]*s[1]*c[2]*cz[1]*cz[2];             // C0*S1*S2*C3
    k[15] = -s[0]*c[1]*c[2]*cz[0]*cz[1];             // S0*S1*C2
    k[16] = -c[0]*s[1]*s[2]*sz[1]*sz[3];             // S1*C2*S3
    k[17] = -s[0]*c[1]*s[2]*sz[0]*sz[1]*cz[2]*cz[3]; // S0*S1*S2*S3
    k[18] = -s[0]*s[1]*c[2]*sz[0]*sz[2];             // S0*C1*S2
    k[19] = -s[0]*s[1]*s[2]*cz[0]*cz[3];             // S0*S3
    // ---- z3 terms (pullback of Z0Z1Z2Z3) ----
    k[20] =  c[0]*c[1]*c[2]*c[3];                    // C0*C2
    k[21] =  c[0]*c[1]*c[2]*s[3]*cz[0]*sz[1]*sz[3];  // S0*S1*S3
    k[22] = -c[0]*c[1]*s[2]*c[3]*cz[2]*cz[3];        // C1*S2*S3
    k[23] =  c[0]*s[1]*c[2]*c[3]*sz[1]*sz[2];        // S1*S2
    k[24] =  s[0]*c[1]*c[2]*c[3]*sz[0]*sz[1];        // S0*S1*C3
    k[25] = -c[0]*c[1]*s[2]*s[3]*sz[0]*cz[1]*sz[2];  // S0*S1*S2*C3
    k[26] = -c[0]*s[1]*c[2]*s[3]*sz[0]*cz[2]*sz[3];  // S0*S2*S3
    k[27] =  c[0]*s[1]*s[2]*c[3]*cz[1]*cz[3];        // C0*S1*S3
    k[28] =  s[0]*c[1]*c[2]*s[3]*cz[3];              // C2*S3
    k[29] = -s[0]*c[1]*s[2]*c[3]*cz[0]*cz[1]*sz[2]*sz[3]; // S0*S1*S2*S3
    k[30] =  s[0]*s[1]*c[2]*c[3]*cz[0]*cz[2];        // S0*S2*C3
    k[31] = -c[0]*s[1]*s[2]*s[3]*cz[0];              // S0*C1*C2*C3
    k[32] = -s[0]*c[1]*s[2]*s[3]*cz[2];              // C0*C1*S2
    k[33] =  s[0]*s[1]*c[2]*s[3]*sz[1]*sz[2]*cz[3];  // C0*S1*S2*S3
    k[34] =  s[0]*s[1]*s[2]*c[3]*sz[0]*sz[3];        // S0*C1*C2*S3
    k[35] =  s[0]*s[1]*s[2]*s[3]*cz[1];              // S1
    // layer0 RY offsets for the main kernel
    k[36] = w[0]; k[37] = w[2]; k[38] = w[4]; k[39] = w[6];
}

__global__ __launch_bounds__(256) void qmain_kernel(
    const float* __restrict__ x, const float* __restrict__ k,
    float* __restrict__ out, int B)
{
    int i = blockIdx.x * blockDim.x + threadIdx.x;
    if (i >= B) return;

    const float4 xv = *reinterpret_cast<const float4*>(x + (size_t)i * 8);
    const float xq[4] = {xv.x, xv.y, xv.z, xv.w};

    float C[4], S[4];
#pragma unroll
    for (int q = 0; q < 4; ++q) {
        float e = __expf(2.f * xq[q]);
        float t = 1.f - 2.f * __builtin_amdgcn_rcpf(1.f + e);   // tanh(x)
        float A = fmaf(3.14159265358979f, t, k[36 + q]);        // pi*tanh + w0
        C[q] = __cosf(A);
        S[q] = __sinf(A);
    }

    // shared pair products
    const float CC = C[0]*C[1], CS = C[0]*S[1], SC = S[0]*C[1], SS = S[0]*S[1];
    const float cc = C[2]*C[3], cs = C[2]*S[3], sc = S[2]*C[3], ss = S[2]*S[3];
    const float S1sc = S[1]*sc;
    const float SSss = SS*ss;

    float z0 = k[0] * (CC*C[3]);
    z0 = fmaf(k[1],  SS*cs,   z0);
    z0 = fmaf(k[2],  ss,      z0);
    z0 = fmaf(k[3],  S1sc,    z0);
    z0 = fmaf(k[4],  SS*S[2], z0);
    z0 = fmaf(k[5],  SC*ss,   z0);
    z0 = fmaf(k[6],  CS*cs,   z0);
    z0 = fmaf(k[7],  S[0],    z0);

    float z1 = k[8] * (C[0]*cc);
    z1 = fmaf(k[9],  S1sc,      z1);
    z1 = fmaf(k[10], SS,        z1);
    z1 = fmaf(k[11], S[0]*S[2], z1);

    float z2 = k[12] * (C[1]*C[3]);
    z2 = fmaf(k[13], C[0]*ss,   z2);
    z2 = fmaf(k[14], CS*sc,     z2);
    z2 = fmaf(k[15], SS*C[2],   z2);
    z2 = fmaf(k[16], S[1]*cs,   z2);
    z2 = fmaf(k[17], SSss,      z2);
    z2 = fmaf(k[18], SC*S[2],   z2);
    z2 = fmaf(k[19], S[0]*S[3], z2);

    float z3 = k[20] * (C[0]*C[2]);
    z3 = fmaf(k[21], SS*S[3],   z3);
    z3 = fmaf(k[22], C[1]*ss,   z3);
    z3 = fmaf(k[23], S[1]*S[2], z3);
    z3 = fmaf(k[24], SS*C[3],   z3);
    z3 = fmaf(k[25], SS*sc,     z3);
    z3 = fmaf(k[26], S[0]*ss,   z3);
    z3 = fmaf(k[27], CS*S[3],   z3);
    z3 = fmaf(k[28], cs,        z3);
    z3 = fmaf(k[29], SSss,      z3);
    z3 = fmaf(k[30], S[0]*sc,   z3);
    z3 = fmaf(k[31], SC*cc,     z3);
    z3 = fmaf(k[32], CC*S[2],   z3);
    z3 = fmaf(k[33], CS*ss,     z3);
    z3 = fmaf(k[34], SC*cs,     z3);
    z3 = fmaf(k[35], S[1],      z3);

    *reinterpret_cast<float4*>(out + (size_t)i * 4) = make_float4(z0, z1, z2, z3);
}

extern "C" void kernel_launch(void* const* d_in, const int* in_sizes, int n_in,
                              void* d_out, int out_size, void* d_ws, size_t ws_size,
                              hipStream_t stream)
{
    const float* x = (const float*)d_in[0];
    const float* w = (const float*)d_in[1];
    float* out = (float*)d_out;
    float* k = (float*)d_ws;            // 40 floats of uniform coefficients
    const int B = in_sizes[0] / 8;      // 524288

    hipLaunchKernelGGL(qsetup_kernel, dim3(1), dim3(64), 0, stream, w, k);

    const int threads = 256;
    const int blocks = (B + threads - 1) / threads;
    hipLaunchKernelGGL(qmain_kernel, dim3(blocks), dim3(threads), 0, stream,
                       x, k, out, B);
}